// Round 11
// baseline (34.447 us; speedup 1.0000x reference)
//
#include <hip/hip_runtime.h>

typedef float f4 __attribute__((ext_vector_type(4)));
typedef float f2 __attribute__((ext_vector_type(2)));
typedef float f32x4 __attribute__((ext_vector_type(4)));
typedef _Float16 f16x8 __attribute__((ext_vector_type(8)));

// h-arena: 32 rows x 1056B, 16B-chunk swizzle (R8-proven).
#define HSWZ16(o) ((o) ^ (((o) >> 3) & 0x70))

// Barrier draining LDS ops only — outstanding GLOBAL loads stay in flight.
#define BARLG() asm volatile("s_waitcnt lgkmcnt(0)\n\ts_barrier" ::: "memory")

__device__ __forceinline__ float ftanh(float x) {
    float e = __expf(2.0f * x);
    return 1.0f - 2.0f / (e + 1.0f);
}
__device__ __forceinline__ float red8(float x) {   // sum over aligned 8-lane groups
    x += __shfl_xor(x, 1); x += __shfl_xor(x, 2); x += __shfl_xor(x, 4);
    return x;
}

// Load one MFMA fragment page DIRECTLY from fp32 W[K][N] (no prep pass):
// lane l holds W[32kt+8*(l>>4)+j][16nt+(l&15)], j=0..7, converted to fp16.
// Per dword-load, lanes 0..15 read 64B contiguous (one row), 4 rows/instr.
template<int N>
__device__ __forceinline__ f16x8 ldfrag(const float* __restrict__ W,
                                        int kt, int nt, int l) {
    const float* p = W + (size_t)(kt * 32 + ((l >> 4) << 3)) * N + nt * 16 + (l & 15);
    f16x8 o;
    #pragma unroll
    for (int j = 0; j < 8; ++j) o[j] = (_Float16)p[j * N];
    return o;
}

// M=32 rows/block, 1024 threads (16 waves), 256 blocks = 1 block/CU.
// R8 dataflow (best: 26.4us), but SINGLE DISPATCH: weight fragments gathered
// straight from fp32 W with inline cvt; no prep kernel, no workspace.
__global__ __launch_bounds__(1024, 4) void scl_mfma(
    const float* __restrict__ cond, const float* __restrict__ act,
    const float* __restrict__ W1, const float* __restrict__ b1,
    const float* __restrict__ W2, const float* __restrict__ b2,
    const float* __restrict__ W3, const float* __restrict__ b3,
    float* __restrict__ out)
{
    // LDS 33792 B:
    //   [0,16896)      x1 [32][264] f16        (dead after L2 reads)
    //   [16896,33792)  x2 [32][264] f16        (dead after L3 MFMAs)
    //   [0,33792)      h: 32 rows x 1056 B, swizzled (overlays x1+x2)
    __shared__ char smem[33792];
    _Float16* x1 = (_Float16*)smem;
    _Float16* x2 = (_Float16*)(smem + 16896);

    const int tid = threadIdx.x;
    const int w   = tid >> 6;   // wave 0..15
    const int l   = tid & 63;
    const int lr  = l & 15;
    const int lg  = l >> 4;
    const int rb  = blockIdx.x * 32;

    // ---- prologue: cond A-frags (2 m-tiles), W1 pages, ALL W2 pages, biases,
    //      act rows for the tail waves.
    f16x8 a1[2][2];
    #pragma unroll
    for (int m = 0; m < 2; ++m) {
        const float* crow = cond + (rb + m * 16 + lr) * 64 + lg * 8;
        #pragma unroll
        for (int kt = 0; kt < 2; ++kt) {
            f4 va = *(const f4*)(crow + kt * 32);
            f4 vb = *(const f4*)(crow + kt * 32 + 4);
            #pragma unroll
            for (int j = 0; j < 4; ++j) {
                a1[m][kt][j]     = (_Float16)va[j];
                a1[m][kt][4 + j] = (_Float16)vb[j];
            }
        }
    }
    f16x8 w1f[2];
    #pragma unroll
    for (int kt = 0; kt < 2; ++kt) w1f[kt] = ldfrag<256>(W1, kt, w, l);
    f16x8 w2f[8];
    #pragma unroll
    for (int kt = 0; kt < 8; ++kt) w2f[kt] = ldfrag<256>(W2, kt, w, l);
    float b1v = b1[w * 16 + lr];
    float b2v = b2[w * 16 + lr];
    float b3v[2];
    #pragma unroll
    for (int n = 0; n < 2; ++n) b3v[n] = b3[(w * 2 + n) * 16 + lr];

    f4 av0 = {}, av1 = {};
    if (w < 4) {   // tail waves: act row = rb + w*8 + (l>>3), cols (l&7)*8..+8
        const float* ap = act + (rb + w * 8 + (l >> 3)) * 64 + (l & 7) * 8;
        av0 = *(const f4*)ap;
        av1 = *(const f4*)(ap + 4);
    }

    // ---------------- layer 1: cond[32x64] @ W1 -> x1 (fp16, bias as C-init)
    {
        f32x4 acc[2] = {{b1v, b1v, b1v, b1v}, {b1v, b1v, b1v, b1v}};
        #pragma unroll
        for (int kt = 0; kt < 2; ++kt)
            #pragma unroll
            for (int m = 0; m < 2; ++m)
                acc[m] = __builtin_amdgcn_mfma_f32_16x16x32_f16(a1[m][kt], w1f[kt], acc[m], 0, 0, 0);
        #pragma unroll
        for (int m = 0; m < 2; ++m)
            #pragma unroll
            for (int r = 0; r < 4; ++r) {
                float v = ftanh(acc[m][r]);   // C/D: col=l&15, row=(l>>4)*4+r
                x1[(m * 16 + lg * 4 + r) * 264 + w * 16 + lr] = (_Float16)v;
            }
    }
    BARLG();

    // ---------------- layer 2 (W3 first half gathered across this phase)
    f16x8 w3a[2][4];
    #pragma unroll
    for (int n = 0; n < 2; ++n)
        #pragma unroll
        for (int kt = 0; kt < 4; ++kt)
            w3a[n][kt] = ldfrag<512>(W3, kt, w * 2 + n, l);
    {
        f32x4 acc[2] = {{b2v, b2v, b2v, b2v}, {b2v, b2v, b2v, b2v}};
        #pragma unroll
        for (int kt = 0; kt < 8; ++kt) {
            int cb = kt * 32 + lg * 8;
            f16x8 am0 = *(const f16x8*)&x1[lr * 264 + cb];
            f16x8 am1 = *(const f16x8*)&x1[(16 + lr) * 264 + cb];
            acc[0] = __builtin_amdgcn_mfma_f32_16x16x32_f16(am0, w2f[kt], acc[0], 0, 0, 0);
            acc[1] = __builtin_amdgcn_mfma_f32_16x16x32_f16(am1, w2f[kt], acc[1], 0, 0, 0);
        }
        #pragma unroll
        for (int m = 0; m < 2; ++m)
            #pragma unroll
            for (int r = 0; r < 4; ++r) {
                float v = ftanh(acc[m][r]);
                x2[(m * 16 + lg * 4 + r) * 264 + w * 16 + lr] = (_Float16)v;
            }
    }
    BARLG();

    // ---------------- layer 3 (W3 second half gathered across the MFMA loop)
    f16x8 w3b[2][4];
    #pragma unroll
    for (int n = 0; n < 2; ++n)
        #pragma unroll
        for (int kt = 0; kt < 4; ++kt)
            w3b[n][kt] = ldfrag<512>(W3, kt + 4, w * 2 + n, l);
    f32x4 acc3[2][2] = {{{b3v[0], b3v[0], b3v[0], b3v[0]}, {b3v[1], b3v[1], b3v[1], b3v[1]}},
                        {{b3v[0], b3v[0], b3v[0], b3v[0]}, {b3v[1], b3v[1], b3v[1], b3v[1]}}};
    #pragma unroll
    for (int kt = 0; kt < 4; ++kt) {
        int cb = kt * 32 + lg * 8;
        f16x8 am0 = *(const f16x8*)&x2[lr * 264 + cb];
        f16x8 am1 = *(const f16x8*)&x2[(16 + lr) * 264 + cb];
        #pragma unroll
        for (int n = 0; n < 2; ++n) {
            acc3[0][n] = __builtin_amdgcn_mfma_f32_16x16x32_f16(am0, w3a[n][kt], acc3[0][n], 0, 0, 0);
            acc3[1][n] = __builtin_amdgcn_mfma_f32_16x16x32_f16(am1, w3a[n][kt], acc3[1][n], 0, 0, 0);
        }
    }
    #pragma unroll
    for (int kt = 4; kt < 8; ++kt) {
        int cb = kt * 32 + lg * 8;
        f16x8 am0 = *(const f16x8*)&x2[lr * 264 + cb];
        f16x8 am1 = *(const f16x8*)&x2[(16 + lr) * 264 + cb];
        #pragma unroll
        for (int n = 0; n < 2; ++n) {
            acc3[0][n] = __builtin_amdgcn_mfma_f32_16x16x32_f16(am0, w3b[n][kt - 4], acc3[0][n], 0, 0, 0);
            acc3[1][n] = __builtin_amdgcn_mfma_f32_16x16x32_f16(am1, w3b[n][kt - 4], acc3[1][n], 0, 0, 0);
        }
    }
    BARLG();   // all x2 reads done block-wide before h overlays x2

    #pragma unroll
    for (int n = 0; n < 2; ++n) {
        int col = (w * 2 + n) * 16 + lr;
        #pragma unroll
        for (int m = 0; m < 2; ++m)
            #pragma unroll
            for (int r = 0; r < 4; ++r) {
                int row = m * 16 + lg * 4 + r;
                *(_Float16*)(smem + row * 1056 + HSWZ16(col * 2)) =
                    (_Float16)acc3[m][n][r];
            }
    }
    BARLG();

    // ---------------- Householder tail: waves 0-3; 8 lanes/row, 8 elems/lane.
    if (w < 4) {
        const int c = l & 7;
        const int hrow = w * 8 + (l >> 3);
        const int grow = rb + hrow;
        f16x8 hv[8];
        #pragma unroll
        for (int j = 0; j < 8; ++j)
            hv[j] = *(const f16x8*)(smem + hrow * 1056 + HSWZ16((c * 8 + j) * 16));
        float h[8][8];   // h[cc][j], column n = 8c+j
        #pragma unroll
        for (int cc = 0; cc < 8; ++cc)
            #pragma unroll
            for (int j = 0; j < 8; ++j)
                h[cc][j] = (float)hv[j][cc];
        float inv[8];
        #pragma unroll
        for (int cc = 0; cc < 8; ++cc) {
            float s = 0.0f;
            #pragma unroll
            for (int j = 0; j < 8; ++j) s += h[cc][j] * h[cc][j];
            inv[cc] = 2.0f / red8(s);
        }
        float u[8] = {av0[0], av0[1], av0[2], av0[3], av1[0], av1[1], av1[2], av1[3]};
        #pragma unroll
        for (int cc = 7; cc >= 0; --cc) {            // a* = E^T Q0..Q7 a
            float d = 0.0f;
            #pragma unroll
            for (int j = 0; j < 8; ++j) d += h[cc][j] * u[j];
            float t = inv[cc] * red8(d);
            #pragma unroll
            for (int j = 0; j < 8; ++j) u[j] -= t * h[cc][j];
        }
        float wv[8];
        #pragma unroll
        for (int j = 0; j < 8; ++j) wv[j] = (c == 0) ? u[j] : 0.0f;   // E a*
        #pragma unroll
        for (int cc = 0; cc < 8; ++cc) {             // q = Q7..Q0 (E a*)
            float d = 0.0f;
            #pragma unroll
            for (int j = 0; j < 8; ++j) d += h[cc][j] * wv[j];
            float t = inv[cc] * red8(d);
            #pragma unroll
            for (int j = 0; j < 8; ++j) wv[j] -= t * h[cc][j];
        }
        f4 o0 = {wv[0], wv[1], wv[2], wv[3]};
        f4 o1 = {wv[4], wv[5], wv[6], wv[7]};
        float* op = out + grow * 64 + c * 8;
        *(f4*)op = o0;
        *(f4*)(op + 4) = o1;
    }
}

extern "C" void kernel_launch(void* const* d_in, const int* in_sizes, int n_in,
                              void* d_out, int out_size, void* d_ws, size_t ws_size,
                              hipStream_t stream) {
    const float* cond = (const float*)d_in[0];
    const float* act  = (const float*)d_in[1];
    const float* W1   = (const float*)d_in[2];
    const float* b1   = (const float*)d_in[3];
    const float* W2   = (const float*)d_in[4];
    const float* b2   = (const float*)d_in[5];
    const float* W3   = (const float*)d_in[6];
    const float* b3   = (const float*)d_in[7];
    float* outp = (float*)d_out;

    scl_mfma<<<dim3(256), dim3(1024), 0, stream>>>(
        cond, act, W1, b1, W2, b2, W3, b3, outp);
}

// Round 12
// 24.627 us; speedup vs baseline: 1.3987x; 1.3987x over previous
//
#include <hip/hip_runtime.h>

typedef float f4 __attribute__((ext_vector_type(4)));
typedef float f32x4 __attribute__((ext_vector_type(4)));
typedef _Float16 f16x8 __attribute__((ext_vector_type(8)));

// Swizzle for the h16 buffer: XOR byte-addr bits 9:7 into bank bits 6:4
// (16B-chunk-preserving, bijective within a 1024B row).
#define HSWZ16(o) ((o) ^ (((o) >> 3) & 0x70))

// Barrier draining LDS ops only — outstanding GLOBAL loads stay in flight.
#define BARLG() asm volatile("s_waitcnt lgkmcnt(0)\n\ts_barrier" ::: "memory")

// ---------- pre-pass: W -> MFMA B-fragment-ordered fp16, fully coalesced ----------
// Page p = nt*KT+kt: 512 f16, lane l holds B[32kt+8*(l>>4)+j][16nt+(l&15)], j=0..7.
// Regions (f16 units): W1 @ 0 (32 pages), W2 @ 16384 (128), W3 @ 81920 (256).
__global__ __launch_bounds__(256) void prep_frags_all(
    const float* __restrict__ W1, const float* __restrict__ W2,
    const float* __restrict__ W3, _Float16* __restrict__ dst) {
    __shared__ float s[32 * 264];
    const int b = blockIdx.x, tid = threadIdx.x;
    const float* W; int N, kt, nh, KT; size_t off;
    if (b < 2)       { W = W1; N = 256; KT = 2; kt = b;            nh = 0;          off = 0; }
    else if (b < 10) { W = W2; N = 256; KT = 8; kt = b - 2;        nh = 0;          off = 16384; }
    else             { W = W3; N = 512; KT = 8; kt = (b - 10) >> 1; nh = (b - 10) & 1; off = 81920; }
    #pragma unroll
    for (int rep = 0; rep < 8; ++rep) {
        int fi = rep * 256 + tid;
        int row = fi >> 6, c4 = fi & 63;
        f4 v = *(const f4*)&W[(kt * 32 + row) * N + nh * 256 + c4 * 4];
        *(f4*)&s[row * 264 + c4 * 4] = v;
    }
    __syncthreads();
    const int wv = tid >> 6, l = tid & 63, lr = l & 15, lg = l >> 4;
    #pragma unroll
    for (int p = 0; p < 4; ++p) {
        int lnt = wv * 4 + p;
        f16x8 o;
        #pragma unroll
        for (int j = 0; j < 8; ++j)
            o[j] = (_Float16)s[(lg * 8 + j) * 264 + lnt * 16 + lr];
        int page = (nh * 16 + lnt) * KT + kt;
        *(f16x8*)&dst[off + (size_t)page * 512 + l * 8] = o;
    }
}

__device__ __forceinline__ float ftanh(float x) {
    float e = __expf(2.0f * x);
    return 1.0f - 2.0f / (e + 1.0f);
}
__device__ __forceinline__ float red8(float x) {   // sum over aligned 8-lane groups
    x += __shfl_xor(x, 1); x += __shfl_xor(x, 2); x += __shfl_xor(x, 4);
    return x;
}

// M=32 rows/block, 1024 threads (16 waves), 256 blocks = 1 block/CU.
// Single fp16 plane for activations (x error ~2^-11, joins the W fp16 error).
// Weight fragments: <=64 VGPR in flight at any time so regalloc keeps them.
__global__ __launch_bounds__(1024, 4) void scl_mfma(
    const float* __restrict__ cond, const float* __restrict__ act,
    const float* __restrict__ b1, const float* __restrict__ b2,
    const float* __restrict__ b3,
    const _Float16* __restrict__ wf,
    float* __restrict__ out)
{
    // LDS 33792 B:
    //   [0,16896)      x1 [32][264] f16        (dead after L2)
    //   [16896,33792)  x2 [32][264] f16        (dead after L3 MFMAs)
    //   [0,33792)      h: 32 rows x 1056 B, swizzled (overlays x1+x2)
    __shared__ char smem[33792];
    _Float16* x1 = (_Float16*)smem;
    _Float16* x2 = (_Float16*)(smem + 16896);

    const int tid = threadIdx.x;
    const int w   = tid >> 6;   // wave 0..15
    const int l   = tid & 63;
    const int lr  = l & 15;
    const int lg  = l >> 4;
    const int rb  = blockIdx.x * 32;
    const f16x8* wp = (const f16x8*)wf;   // page stride 64 (f16x8 units)

    // ---- prologue loads: cond (2 m-tiles), W1 (2 pages), W2 (8 pages), biases,
    //      act rows for the tail waves.
    f16x8 a1[2][2];
    #pragma unroll
    for (int m = 0; m < 2; ++m) {
        const float* crow = cond + (rb + m * 16 + lr) * 64 + lg * 8;
        #pragma unroll
        for (int kt = 0; kt < 2; ++kt) {
            f4 va = *(const f4*)(crow + kt * 32);
            f4 vb = *(const f4*)(crow + kt * 32 + 4);
            #pragma unroll
            for (int j = 0; j < 4; ++j) {
                a1[m][kt][j]     = (_Float16)va[j];
                a1[m][kt][4 + j] = (_Float16)vb[j];
            }
        }
    }
    f16x8 w1f[2];
    #pragma unroll
    for (int kt = 0; kt < 2; ++kt) w1f[kt] = wp[(w * 2 + kt) * 64 + l];
    f16x8 w2f[8];
    #pragma unroll
    for (int kt = 0; kt < 8; ++kt) w2f[kt] = wp[2048 + (w * 8 + kt) * 64 + l];
    float b1v = b1[w * 16 + lr];
    float b2v = b2[w * 16 + lr];
    float b3v[2];
    #pragma unroll
    for (int n = 0; n < 2; ++n) b3v[n] = b3[(w * 2 + n) * 16 + lr];

    f4 av0 = {}, av1 = {};
    if (w < 4) {   // tail waves: act row = rb + w*8 + (l>>3), cols (l&7)*8..+8
        const float* ap = act + (rb + w * 8 + (l >> 3)) * 64 + (l & 7) * 8;
        av0 = *(const f4*)ap;
        av1 = *(const f4*)(ap + 4);
    }

    // ---------------- layer 1: cond[32x64] @ W1 -> x1 (fp16, single plane)
    {
        f32x4 acc[2] = {};
        #pragma unroll
        for (int kt = 0; kt < 2; ++kt)
            #pragma unroll
            for (int m = 0; m < 2; ++m)
                acc[m] = __builtin_amdgcn_mfma_f32_16x16x32_f16(a1[m][kt], w1f[kt], acc[m], 0, 0, 0);
        #pragma unroll
        for (int m = 0; m < 2; ++m)
            #pragma unroll
            for (int r = 0; r < 4; ++r) {
                float v = ftanh(acc[m][r] + b1v);   // C/D: col=l&15, row=(l>>4)*4+r
                x1[(m * 16 + lg * 4 + r) * 264 + w * 16 + lr] = (_Float16)v;
            }
    }
    BARLG();

    // ---------------- layer 2 (W3 first half prefetched across this phase)
    f16x8 w3a[2][4];
    #pragma unroll
    for (int n = 0; n < 2; ++n)
        #pragma unroll
        for (int kt = 0; kt < 4; ++kt)
            w3a[n][kt] = wp[10240 + ((w * 2 + n) * 8 + kt) * 64 + l];
    {
        f32x4 acc[2] = {};
        #pragma unroll
        for (int kt = 0; kt < 8; ++kt) {
            int cb = kt * 32 + lg * 8;
            f16x8 am0 = *(const f16x8*)&x1[lr * 264 + cb];
            f16x8 am1 = *(const f16x8*)&x1[(16 + lr) * 264 + cb];
            acc[0] = __builtin_amdgcn_mfma_f32_16x16x32_f16(am0, w2f[kt], acc[0], 0, 0, 0);
            acc[1] = __builtin_amdgcn_mfma_f32_16x16x32_f16(am1, w2f[kt], acc[1], 0, 0, 0);
        }
        #pragma unroll
        for (int m = 0; m < 2; ++m)
            #pragma unroll
            for (int r = 0; r < 4; ++r) {
                float v = ftanh(acc[m][r] + b2v);
                x2[(m * 16 + lg * 4 + r) * 264 + w * 16 + lr] = (_Float16)v;
            }
    }
    BARLG();

    // ---------------- layer 3 (W3 second half prefetched across the MFMA loop)
    f16x8 w3b[2][4];
    #pragma unroll
    for (int n = 0; n < 2; ++n)
        #pragma unroll
        for (int kt = 0; kt < 4; ++kt)
            w3b[n][kt] = wp[10240 + ((w * 2 + n) * 8 + (kt + 4)) * 64 + l];
    f32x4 acc3[2][2] = {};
    #pragma unroll
    for (int kt = 0; kt < 4; ++kt) {
        int cb = kt * 32 + lg * 8;
        f16x8 am0 = *(const f16x8*)&x2[lr * 264 + cb];
        f16x8 am1 = *(const f16x8*)&x2[(16 + lr) * 264 + cb];
        #pragma unroll
        for (int n = 0; n < 2; ++n) {
            acc3[0][n] = __builtin_amdgcn_mfma_f32_16x16x32_f16(am0, w3a[n][kt], acc3[0][n], 0, 0, 0);
            acc3[1][n] = __builtin_amdgcn_mfma_f32_16x16x32_f16(am1, w3a[n][kt], acc3[1][n], 0, 0, 0);
        }
    }
    #pragma unroll
    for (int kt = 4; kt < 8; ++kt) {
        int cb = kt * 32 + lg * 8;
        f16x8 am0 = *(const f16x8*)&x2[lr * 264 + cb];
        f16x8 am1 = *(const f16x8*)&x2[(16 + lr) * 264 + cb];
        #pragma unroll
        for (int n = 0; n < 2; ++n) {
            acc3[0][n] = __builtin_amdgcn_mfma_f32_16x16x32_f16(am0, w3b[n][kt - 4], acc3[0][n], 0, 0, 0);
            acc3[1][n] = __builtin_amdgcn_mfma_f32_16x16x32_f16(am1, w3b[n][kt - 4], acc3[1][n], 0, 0, 0);
        }
    }
    BARLG();   // all x2 reads done block-wide before h overlays x2

    #pragma unroll
    for (int n = 0; n < 2; ++n) {
        int col = (w * 2 + n) * 16 + lr;
        #pragma unroll
        for (int m = 0; m < 2; ++m)
            #pragma unroll
            for (int r = 0; r < 4; ++r) {
                int row = m * 16 + lg * 4 + r;
                *(_Float16*)(smem + row * 1056 + HSWZ16(col * 2)) =
                    (_Float16)(acc3[m][n][r] + b3v[n]);
            }
    }
    BARLG();

    // ---------------- Householder tail: waves 0-3 only; 8 lanes/row, 8 elems/lane.
    // Lane (w, l>>3 = row-in-group, c = l&7) owns columns n = 8c..8c+7.
    // h chunk for column n = bytes [n*16, n*16+16) of the row = h[cc=0..7][n].
    if (w < 4) {
        const int c = l & 7;
        const int hrow = w * 8 + (l >> 3);
        const int grow = rb + hrow;
        f16x8 hv[8];
        #pragma unroll
        for (int j = 0; j < 8; ++j)
            hv[j] = *(const f16x8*)(smem + hrow * 1056 + HSWZ16((c * 8 + j) * 16));
        float h[8][8];   // h[cc][j], j -> column 8c+j
        #pragma unroll
        for (int cc = 0; cc < 8; ++cc)
            #pragma unroll
            for (int j = 0; j < 8; ++j)
                h[cc][j] = (float)hv[j][cc];
        float inv[8];
        #pragma unroll
        for (int cc = 0; cc < 8; ++cc) {
            float s = 0.0f;
            #pragma unroll
            for (int j = 0; j < 8; ++j) s += h[cc][j] * h[cc][j];
            inv[cc] = 2.0f / red8(s);
        }
        float u[8] = {av0[0], av0[1], av0[2], av0[3], av1[0], av1[1], av1[2], av1[3]};
        #pragma unroll
        for (int cc = 7; cc >= 0; --cc) {           // a* = E^T Q0..Q7 a
            float d = 0.0f;
            #pragma unroll
            for (int j = 0; j < 8; ++j) d += h[cc][j] * u[j];
            float t = inv[cc] * red8(d);
            #pragma unroll
            for (int j = 0; j < 8; ++j) u[j] -= t * h[cc][j];
        }
        float wv[8];
        #pragma unroll
        for (int j = 0; j < 8; ++j) wv[j] = (c == 0) ? u[j] : 0.0f;   // E a*
        #pragma unroll
        for (int cc = 0; cc < 8; ++cc) {            // q = Q7..Q0 (E a*)
            float d = 0.0f;
            #pragma unroll
            for (int j = 0; j < 8; ++j) d += h[cc][j] * wv[j];
            float t = inv[cc] * red8(d);
            #pragma unroll
            for (int j = 0; j < 8; ++j) wv[j] -= t * h[cc][j];
        }
        f4 o0 = {wv[0], wv[1], wv[2], wv[3]};
        f4 o1 = {wv[4], wv[5], wv[6], wv[7]};
        float* op = out + grow * 64 + c * 8;
        *(f4*)op = o0;
        *(f4*)(op + 4) = o1;
    }
}

extern "C" void kernel_launch(void* const* d_in, const int* in_sizes, int n_in,
                              void* d_out, int out_size, void* d_ws, size_t ws_size,
                              hipStream_t stream) {
    const float* cond = (const float*)d_in[0];
    const float* act  = (const float*)d_in[1];
    const float* W1   = (const float*)d_in[2];
    const float* b1   = (const float*)d_in[3];
    const float* W2   = (const float*)d_in[4];
    const float* b2   = (const float*)d_in[5];
    const float* W3   = (const float*)d_in[6];
    const float* b3   = (const float*)d_in[7];
    float* outp = (float*)d_out;

    _Float16* wf = (_Float16*)d_ws;   // 425984 bytes
    prep_frags_all<<<dim3(26), dim3(256), 0, stream>>>(W1, W2, W3, wf);
    scl_mfma<<<dim3(256), dim3(1024), 0, stream>>>(cond, act, b1, b2, b3, wf, outp);
}